// Round 2
// baseline (393.764 us; speedup 1.0000x reference)
//
#include <hip/hip_runtime.h>
#include <cstddef>

// SASRec inference, fp32 correctness-first baseline.
// Round 2 fix: key/query masks derived from input_ids (f64-reference
// semantics) instead of fp32 knife-edge row sums (LN1 row-sum is
// mathematically 0 -> sign(|sum|) is stochastic in fp32).

#define NITEMS 200000
#define Bsz 512
#define Ssz 64
#define Dsz 64
#define LS 65            // padded LDS row stride (floats) -> 2-way banks max
#define EPSV 1e-3f
#define NEGV (-4294967295.0f)   // -2^32 + 1

static __device__ __forceinline__ float wsum(float v){
#pragma unroll
  for (int o = 32; o > 0; o >>= 1) v += __shfl_xor(v, o, 64);
  return v;
}
static __device__ __forceinline__ float wmax(float v){
#pragma unroll
  for (int o = 32; o > 0; o >>= 1) v = fmaxf(v, __shfl_xor(v, o, 64));
  return v;
}

// ---------------------------------------------------------------- embed ----
__global__ __launch_bounds__(256) void k_embed(const int* __restrict__ ids,
    const float* __restrict__ item_emb, const float* __restrict__ pos_emb,
    float* __restrict__ seq){
  int e4 = blockIdx.x * 256 + threadIdx.x;      // float4 index over [B*S][16]
  int d4 = e4 & 15, bs = e4 >> 4, s = bs & 63;
  int id = ids[bs];
  float4 r = make_float4(0.f, 0.f, 0.f, 0.f);
  if (id != NITEMS){
    float4 a = ((const float4*)(item_emb + (size_t)id * 64))[d4];
    float4 p = ((const float4*)(pos_emb + s * 64))[d4];
    r = make_float4(a.x + p.x, a.y + p.y, a.z + p.z, a.w + p.w);
  }
  ((float4*)seq)[e4] = r;
}

// ------------------------------------------------------------ layer GEMMs --
// stage a 64x64 weight matrix from global into LDS (row-major preserved)
static __device__ __forceinline__ void stage_w(float sW[64][64],
    const float* __restrict__ Wg, int t){
  __syncthreads();                 // previous consumers of sW / producers of A
#pragma unroll
  for (int it = 0; it < 4; ++it){
    int e4 = t + 256 * it;         // 1024 float4
    float4 v = ((const float4*)Wg)[e4];
    *(float4*)&sW[e4 >> 4][(e4 & 15) * 4] = v;
  }
  __syncthreads();
}

// C[4ty+i][4tx+j] += sum_kk A[4ty+i][kk] * W[kk][4tx+j]   (W unpadded)
static __device__ __forceinline__ void gemm_w(const float A[64][LS],
    const float sW[64][64], int ty, int tx, float acc[4][4]){
  for (int kk = 0; kk < 64; ++kk){
    float a[4];
#pragma unroll
    for (int i = 0; i < 4; ++i) a[i] = A[ty*4 + i][kk];
    float4 w4 = *(const float4*)&sW[kk][tx*4];
    float w[4] = {w4.x, w4.y, w4.z, w4.w};
#pragma unroll
    for (int i = 0; i < 4; ++i)
#pragma unroll
      for (int j = 0; j < 4; ++j) acc[i][j] = fmaf(a[i], w[j], acc[i][j]);
  }
}

// C += A * B^T  (both padded LDS):  C[r][c] = sum_kk A[r][kk]*Bm[c][kk]
static __device__ __forceinline__ void gemm_bt(const float A[64][LS],
    const float Bm[64][LS], int ty, int tx, float acc[4][4]){
  for (int kk = 0; kk < 64; ++kk){
    float a[4], w[4];
#pragma unroll
    for (int i = 0; i < 4; ++i) a[i] = A[ty*4 + i][kk];
#pragma unroll
    for (int j = 0; j < 4; ++j) w[j] = Bm[tx*4 + j][kk];
#pragma unroll
    for (int i = 0; i < 4; ++i)
#pragma unroll
      for (int j = 0; j < 4; ++j) acc[i][j] = fmaf(a[i], w[j], acc[i][j]);
  }
}

// C += A * Wp  where Wp is a padded LDS matrix (e.g. V):  sum_kk A[r][kk]*Wp[kk][c]
static __device__ __forceinline__ void gemm_wp(const float A[64][LS],
    const float Wp[64][LS], int ty, int tx, float acc[4][4]){
  for (int kk = 0; kk < 64; ++kk){
    float a[4], w[4];
#pragma unroll
    for (int i = 0; i < 4; ++i) a[i] = A[ty*4 + i][kk];
#pragma unroll
    for (int j = 0; j < 4; ++j) w[j] = Wp[kk][tx*4 + j];
#pragma unroll
    for (int i = 0; i < 4; ++i)
#pragma unroll
      for (int j = 0; j < 4; ++j) acc[i][j] = fmaf(a[i], w[j], acc[i][j]);
  }
}

// ------------------------------------------------------ fused block layer --
__global__ __launch_bounds__(256) void k_layer(float* __restrict__ seq_g,
    const int* __restrict__ ids,
    const float* __restrict__ ln1g, const float* __restrict__ ln1b,
    const float* __restrict__ Wq, const float* __restrict__ bq,
    const float* __restrict__ Wk, const float* __restrict__ bk,
    const float* __restrict__ Wv, const float* __restrict__ bv,
    const float* __restrict__ ln2g, const float* __restrict__ ln2b,
    const float* __restrict__ W1, const float* __restrict__ b1,
    const float* __restrict__ W2, const float* __restrict__ b2){
  __shared__ float sA[64][LS];   // raw seq -> later x2 (LN2 out)
  __shared__ float sq[64][LS];   // LN1 out (queries / residual)
  __shared__ float sQ[64][LS];   // Q proj -> later x (attn + q)
  __shared__ float sK[64][LS];
  __shared__ float sV[64][LS];
  __shared__ float sP[64][LS];   // scores/attn -> later h (FFN hidden)
  __shared__ float sW[64][64];
  __shared__ float s_msk[64];    // padding mask == key mask == query mask (f64 semantics)

  const int t = threadIdx.x;
  const int lane = t & 63, wid = t >> 6;
  const int tx = t & 15, ty = t >> 4;
  const int b = blockIdx.x;
  float* seq_b = seq_g + (size_t)b * Ssz * Dsz;

  // load the sequence tile
#pragma unroll
  for (int it = 0; it < 4; ++it){
    int e4 = t + 256 * it;
    int r = e4 >> 4, c = (e4 & 15) * 4;
    float4 v = ((const float4*)seq_b)[e4];
    sA[r][c+0] = v.x; sA[r][c+1] = v.y; sA[r][c+2] = v.z; sA[r][c+3] = v.w;
  }
  if (t < 64) s_msk[t] = (ids[b * Ssz + t] != NITEMS) ? 1.f : 0.f;
  __syncthreads();

  // LN1 (one wave per row, 16 rows per wave)
  for (int r = wid; r < 64; r += 4){
    float x = sA[r][lane];
    float mu = wsum(x) * (1.f / 64.f);
    float dv = x - mu;
    float var = wsum(dv * dv) * (1.f / 64.f);
    sq[r][lane] = dv * (1.f / sqrtf(var + EPSV)) * ln1g[lane] + ln1b[lane];
  }
  __syncthreads();

  // Q = LN1(seq) @ Wq + bq
  stage_w(sW, Wq, t);
  { float acc[4][4] = {};
    gemm_w(sq, sW, ty, tx, acc);
    float4 b4 = *(const float4*)&bq[tx*4];
    float bb[4] = {b4.x, b4.y, b4.z, b4.w};
#pragma unroll
    for (int i = 0; i < 4; ++i)
#pragma unroll
      for (int j = 0; j < 4; ++j) sQ[ty*4+i][tx*4+j] = acc[i][j] + bb[j];
  }
  // K = seq @ Wk + bk
  stage_w(sW, Wk, t);
  { float acc[4][4] = {};
    gemm_w(sA, sW, ty, tx, acc);
    float4 b4 = *(const float4*)&bk[tx*4];
    float bb[4] = {b4.x, b4.y, b4.z, b4.w};
#pragma unroll
    for (int i = 0; i < 4; ++i)
#pragma unroll
      for (int j = 0; j < 4; ++j) sK[ty*4+i][tx*4+j] = acc[i][j] + bb[j];
  }
  // V = seq @ Wv + bv
  stage_w(sW, Wv, t);
  { float acc[4][4] = {};
    gemm_w(sA, sW, ty, tx, acc);
    float4 b4 = *(const float4*)&bv[tx*4];
    float bb[4] = {b4.x, b4.y, b4.z, b4.w};
#pragma unroll
    for (int i = 0; i < 4; ++i)
#pragma unroll
      for (int j = 0; j < 4; ++j) sV[ty*4+i][tx*4+j] = acc[i][j] + bb[j];
  }
  __syncthreads();

  // scores = Q @ K^T  (raw dot; scale applied in softmax)
  { float acc[4][4] = {};
    gemm_bt(sQ, sK, ty, tx, acc);
#pragma unroll
    for (int i = 0; i < 4; ++i)
#pragma unroll
      for (int j = 0; j < 4; ++j) sP[ty*4+i][tx*4+j] = acc[i][j];
  }
  __syncthreads();

  // masked softmax per row + query mask
  for (int r = wid; r < 64; r += 4){
    float raw = sP[r][lane];
    bool valid = (lane <= r) && (s_msk[lane] != 0.f);
    float sc = valid ? raw * 0.125f : NEGV;
    float m = wmax(sc);
    float e = __expf(sc - m);
    float ssumv = wsum(e);
    sP[r][lane] = (e / ssumv) * s_msk[r];
  }
  __syncthreads();

  // x = attn @ V + q   -> sQ
  { float acc[4][4] = {};
    gemm_wp(sP, sV, ty, tx, acc);
#pragma unroll
    for (int i = 0; i < 4; ++i)
#pragma unroll
      for (int j = 0; j < 4; ++j){
        int r = ty*4+i, c = tx*4+j;
        sQ[r][c] = acc[i][j] + sq[r][c];
      }
  }
  __syncthreads();

  // LN2: sQ -> sA (x2; also FFN residual)
  for (int r = wid; r < 64; r += 4){
    float x = sQ[r][lane];
    float mu = wsum(x) * (1.f / 64.f);
    float dv = x - mu;
    float var = wsum(dv * dv) * (1.f / 64.f);
    sA[r][lane] = dv * (1.f / sqrtf(var + EPSV)) * ln2g[lane] + ln2b[lane];
  }
  // h = relu(x2 @ W1 + b1) -> sP   (stage_w's leading sync covers sA writes)
  stage_w(sW, W1, t);
  { float acc[4][4] = {};
    gemm_w(sA, sW, ty, tx, acc);
    float4 b4 = *(const float4*)&b1[tx*4];
    float bb[4] = {b4.x, b4.y, b4.z, b4.w};
#pragma unroll
    for (int i = 0; i < 4; ++i)
#pragma unroll
      for (int j = 0; j < 4; ++j)
        sP[ty*4+i][tx*4+j] = fmaxf(acc[i][j] + bb[j], 0.f);
  }
  // out = (h @ W2 + b2 + x2) * mask -> global seq
  stage_w(sW, W2, t);
  { float acc[4][4] = {};
    gemm_w(sP, sW, ty, tx, acc);
    float4 b4 = *(const float4*)&b2[tx*4];
    float bb[4] = {b4.x, b4.y, b4.z, b4.w};
#pragma unroll
    for (int i = 0; i < 4; ++i){
      int r = ty*4+i;
      float m = s_msk[r];
      float4 o;
      o.x = (acc[i][0] + bb[0] + sA[r][tx*4+0]) * m;
      o.y = (acc[i][1] + bb[1] + sA[r][tx*4+1]) * m;
      o.z = (acc[i][2] + bb[2] + sA[r][tx*4+2]) * m;
      o.w = (acc[i][3] + bb[3] + sA[r][tx*4+3]) * m;
      *(float4*)&seq_b[r*64 + tx*4] = o;
    }
  }
}

// ------------------------------------------------------------- final LN ----
__global__ __launch_bounds__(64) void k_lnf(const float* __restrict__ seq,
    const float* __restrict__ g, const float* __restrict__ be,
    float* __restrict__ semb){
  int b = blockIdx.x, lane = threadIdx.x;
  float x = seq[(size_t)b * Ssz * Dsz + 63 * 64 + lane];
  float mu = wsum(x) * (1.f / 64.f);
  float dv = x - mu;
  float var = wsum(dv * dv) * (1.f / 64.f);
  semb[b * 64 + lane] = dv * (1.f / sqrtf(var + EPSV)) * g[lane] + be[lane];
}

// --------------------------------------------------------------- scoring ---
// out[b][i] = sum_d E[b][d] * T[i][d] ; 128x128 tile per WG, 8x8 per thread.
__global__ __launch_bounds__(256) void k_score(const float* __restrict__ E,
    const float* __restrict__ T, float* __restrict__ out){
  __shared__ float sE[64][132];   // [d][b-local], padded
  __shared__ float sT[64][132];   // [d][i-local], padded
  const int t = threadIdx.x;
  const int tx = t & 15, ty = t >> 4;
  const int i0 = blockIdx.x * 128;
  const int b0 = blockIdx.y * 128;

#pragma unroll
  for (int it = 0; it < 8; ++it){
    int e4 = t + 256 * it;                 // 2048 float4 over [128][16]
    int r = e4 >> 4, c = (e4 & 15) * 4;
    float4 v = ((const float4*)(E + (size_t)(b0 + r) * 64))[e4 & 15];
    sE[c+0][r] = v.x; sE[c+1][r] = v.y; sE[c+2][r] = v.z; sE[c+3][r] = v.w;
  }
#pragma unroll
  for (int it = 0; it < 8; ++it){
    int e4 = t + 256 * it;
    int r = e4 >> 4, c = (e4 & 15) * 4;
    int i = i0 + r;
    float4 v = make_float4(0.f, 0.f, 0.f, 0.f);
    if (i < NITEMS) v = ((const float4*)(T + (size_t)i * 64))[e4 & 15];
    sT[c+0][r] = v.x; sT[c+1][r] = v.y; sT[c+2][r] = v.z; sT[c+3][r] = v.w;
  }
  __syncthreads();

  float acc[8][8];
#pragma unroll
  for (int i = 0; i < 8; ++i)
#pragma unroll
    for (int j = 0; j < 8; ++j) acc[i][j] = 0.f;

  for (int kk = 0; kk < 64; ++kk){
    float4 a0 = *(const float4*)&sE[kk][ty*8];
    float4 a1 = *(const float4*)&sE[kk][ty*8 + 4];
    float4 w0 = *(const float4*)&sT[kk][tx*8];
    float4 w1 = *(const float4*)&sT[kk][tx*8 + 4];
    float a[8] = {a0.x, a0.y, a0.z, a0.w, a1.x, a1.y, a1.z, a1.w};
    float w[8] = {w0.x, w0.y, w0.z, w0.w, w1.x, w1.y, w1.z, w1.w};
#pragma unroll
    for (int i = 0; i < 8; ++i)
#pragma unroll
      for (int j = 0; j < 8; ++j) acc[i][j] = fmaf(a[i], w[j], acc[i][j]);
  }

  int ib = i0 + tx * 8;
  if (ib < NITEMS){
#pragma unroll
    for (int ii = 0; ii < 8; ++ii){
      float* orow = out + (size_t)(b0 + ty*8 + ii) * NITEMS + ib;
      ((float4*)orow)[0] = make_float4(acc[ii][0], acc[ii][1], acc[ii][2], acc[ii][3]);
      ((float4*)orow)[1] = make_float4(acc[ii][4], acc[ii][5], acc[ii][6], acc[ii][7]);
    }
  }
}

// ----------------------------------------------------------------- launch --
extern "C" void kernel_launch(void* const* d_in, const int* in_sizes, int n_in,
                              void* d_out, int out_size, void* d_ws, size_t ws_size,
                              hipStream_t stream){
  const int*   ids      = (const int*)  d_in[0];
  const float* item_emb = (const float*)d_in[1];
  const float* pos_emb  = (const float*)d_in[2];
  const float* ln1g     = (const float*)d_in[3];
  const float* ln1b     = (const float*)d_in[4];
  const float* Wq       = (const float*)d_in[5];
  const float* bq       = (const float*)d_in[6];
  const float* Wk       = (const float*)d_in[7];
  const float* bk       = (const float*)d_in[8];
  const float* Wv       = (const float*)d_in[9];
  const float* bv       = (const float*)d_in[10];
  const float* ln2g     = (const float*)d_in[11];
  const float* ln2b     = (const float*)d_in[12];
  const float* W1       = (const float*)d_in[13];
  const float* b1       = (const float*)d_in[14];
  const float* W2       = (const float*)d_in[15];
  const float* b2       = (const float*)d_in[16];
  const float* lnfg     = (const float*)d_in[17];
  const float* lnfb     = (const float*)d_in[18];
  const float* items    = (const float*)d_in[19];
  float* out  = (float*)d_out;
  float* seq  = (float*)d_ws;                       // 512*64*64 f32 = 8 MB
  float* semb = seq + (size_t)Bsz * Ssz * Dsz;      // 512*64 f32

  k_embed<<<2048, 256, 0, stream>>>(ids, item_emb, pos_emb, seq);
  for (int l = 0; l < 2; ++l)
    k_layer<<<Bsz, 256, 0, stream>>>(seq, ids,
        ln1g + l*64, ln1b + l*64,
        Wq + l*4096, bq + l*64, Wk + l*4096, bk + l*64, Wv + l*4096, bv + l*64,
        ln2g + l*64, ln2b + l*64,
        W1 + l*4096, b1 + l*64, W2 + l*4096, b2 + l*64);
  k_lnf<<<Bsz, 64, 0, stream>>>(seq, lnfg, lnfb, semb);
  k_score<<<dim3(1563, 4), 256, 0, stream>>>(semb, items, out);
}

// Round 3
// 295.106 us; speedup vs baseline: 1.3343x; 1.3343x over previous
//
#include <hip/hip_runtime.h>
#include <cstddef>

// SASRec inference. Round 3: k_score via bf16 MFMA with hi/lo split (fp32-
// accurate), k_layer widened to 512 threads (8 waves/CU) for latency hiding.

#define NITEMS 200000
#define Bsz 512
#define Ssz 64
#define Dsz 64
#define LS 65            // padded LDS row stride (floats)
#define EPSV 1e-3f
#define NEGV (-4294967295.0f)   // -2^32 + 1

typedef __attribute__((ext_vector_type(8))) short short8;   // 8 bf16 (4 VGPRs)
typedef __attribute__((ext_vector_type(4))) float f32x4;

static __device__ __forceinline__ float wsum(float v){
#pragma unroll
  for (int o = 32; o > 0; o >>= 1) v += __shfl_xor(v, o, 64);
  return v;
}
static __device__ __forceinline__ float wmax(float v){
#pragma unroll
  for (int o = 32; o > 0; o >>= 1) v = fmaxf(v, __shfl_xor(v, o, 64));
  return v;
}

// bf16 round-to-nearest-even (finite inputs only)
static __device__ __forceinline__ unsigned short f2b(float f){
  unsigned u = __float_as_uint(f);
  unsigned r = u + 0x7fffu + ((u >> 16) & 1u);
  return (unsigned short)(r >> 16);
}
static __device__ __forceinline__ float b2f(unsigned short h){
  return __uint_as_float(((unsigned)h) << 16);
}

// ---------------------------------------------------------------- embed ----
__global__ __launch_bounds__(256) void k_embed(const int* __restrict__ ids,
    const float* __restrict__ item_emb, const float* __restrict__ pos_emb,
    float* __restrict__ seq){
  int e4 = blockIdx.x * 256 + threadIdx.x;      // float4 index over [B*S][16]
  int d4 = e4 & 15, bs = e4 >> 4, s = bs & 63;
  int id = ids[bs];
  float4 r = make_float4(0.f, 0.f, 0.f, 0.f);
  if (id != NITEMS){
    float4 a = ((const float4*)(item_emb + (size_t)id * 64))[d4];
    float4 p = ((const float4*)(pos_emb + s * 64))[d4];
    r = make_float4(a.x + p.x, a.y + p.y, a.z + p.z, a.w + p.w);
  }
  ((float4*)seq)[e4] = r;
}

// ------------------------------------------------------------ layer GEMMs --
// stage a 64x64 weight matrix into LDS (512 threads)
static __device__ __forceinline__ void stage_w(float sW[64][64],
    const float* __restrict__ Wg, int t){
  __syncthreads();
#pragma unroll
  for (int it = 0; it < 2; ++it){
    int e4 = t + 512 * it;         // 1024 float4
    float4 v = ((const float4*)Wg)[e4];
    *(float4*)&sW[e4 >> 4][(e4 & 15) * 4] = v;
  }
  __syncthreads();
}

// acc[i][j] += sum_kk A[ty*2+i][kk] * W[kk][tx*4+j]
static __device__ __forceinline__ void gemm_w2(const float A[64][LS],
    const float sW[64][64], int ty, int tx, float acc[2][4]){
  for (int kk = 0; kk < 64; ++kk){
    float a0 = A[ty*2][kk], a1 = A[ty*2+1][kk];
    float4 w4 = *(const float4*)&sW[kk][tx*4];
    float w[4] = {w4.x, w4.y, w4.z, w4.w};
#pragma unroll
    for (int j = 0; j < 4; ++j){
      acc[0][j] = fmaf(a0, w[j], acc[0][j]);
      acc[1][j] = fmaf(a1, w[j], acc[1][j]);
    }
  }
}

// acc[i][j] += sum_kk A[ty*2+i][kk] * Bm[tx*4+j][kk]
static __device__ __forceinline__ void gemm_bt2(const float A[64][LS],
    const float Bm[64][LS], int ty, int tx, float acc[2][4]){
  for (int kk = 0; kk < 64; ++kk){
    float a0 = A[ty*2][kk], a1 = A[ty*2+1][kk];
    float w[4];
#pragma unroll
    for (int j = 0; j < 4; ++j) w[j] = Bm[tx*4 + j][kk];
#pragma unroll
    for (int j = 0; j < 4; ++j){
      acc[0][j] = fmaf(a0, w[j], acc[0][j]);
      acc[1][j] = fmaf(a1, w[j], acc[1][j]);
    }
  }
}

// acc[i][j] += sum_kk A[ty*2+i][kk] * Wp[kk][tx*4+j]   (padded LDS matrix)
static __device__ __forceinline__ void gemm_wp2(const float A[64][LS],
    const float Wp[64][LS], int ty, int tx, float acc[2][4]){
  for (int kk = 0; kk < 64; ++kk){
    float a0 = A[ty*2][kk], a1 = A[ty*2+1][kk];
    float w[4];
#pragma unroll
    for (int j = 0; j < 4; ++j) w[j] = Wp[kk][tx*4 + j];
#pragma unroll
    for (int j = 0; j < 4; ++j){
      acc[0][j] = fmaf(a0, w[j], acc[0][j]);
      acc[1][j] = fmaf(a1, w[j], acc[1][j]);
    }
  }
}

// ------------------------------------------------------ fused block layer --
__global__ __launch_bounds__(512) void k_layer(float* __restrict__ seq_g,
    const int* __restrict__ ids,
    const float* __restrict__ ln1g, const float* __restrict__ ln1b,
    const float* __restrict__ Wq, const float* __restrict__ bq,
    const float* __restrict__ Wk, const float* __restrict__ bk,
    const float* __restrict__ Wv, const float* __restrict__ bv,
    const float* __restrict__ ln2g, const float* __restrict__ ln2b,
    const float* __restrict__ W1, const float* __restrict__ b1,
    const float* __restrict__ W2, const float* __restrict__ b2){
  __shared__ float sA[64][LS];   // raw seq -> later x2 (LN2 out)
  __shared__ float sq[64][LS];   // LN1 out (queries / residual)
  __shared__ float sQ[64][LS];   // Q proj -> later x (attn + q)
  __shared__ float sK[64][LS];
  __shared__ float sV[64][LS];
  __shared__ float sP[64][LS];   // scores/attn -> later h (FFN hidden)
  __shared__ float sW[64][64];
  __shared__ float s_msk[64];

  const int t = threadIdx.x;
  const int lane = t & 63, wid = t >> 6;   // 8 waves
  const int tx = t & 15, ty = t >> 4;      // ty 0..31
  const int b = blockIdx.x;
  float* seq_b = seq_g + (size_t)b * Ssz * Dsz;

  // load the sequence tile (1024 float4, 2 per thread)
#pragma unroll
  for (int it = 0; it < 2; ++it){
    int e4 = t + 512 * it;
    int r = e4 >> 4, c = (e4 & 15) * 4;
    float4 v = ((const float4*)seq_b)[e4];
    sA[r][c+0] = v.x; sA[r][c+1] = v.y; sA[r][c+2] = v.z; sA[r][c+3] = v.w;
  }
  if (t < 64) s_msk[t] = (ids[b * Ssz + t] != NITEMS) ? 1.f : 0.f;
  __syncthreads();

  // LN1 (one wave per row, 8 rows per wave)
  for (int r = wid; r < 64; r += 8){
    float x = sA[r][lane];
    float mu = wsum(x) * (1.f / 64.f);
    float dv = x - mu;
    float var = wsum(dv * dv) * (1.f / 64.f);
    sq[r][lane] = dv * (1.f / sqrtf(var + EPSV)) * ln1g[lane] + ln1b[lane];
  }
  __syncthreads();

  // Q = LN1(seq) @ Wq + bq
  stage_w(sW, Wq, t);
  { float acc[2][4] = {};
    gemm_w2(sq, sW, ty, tx, acc);
    float4 b4 = *(const float4*)&bq[tx*4];
    float bb[4] = {b4.x, b4.y, b4.z, b4.w};
#pragma unroll
    for (int i = 0; i < 2; ++i)
#pragma unroll
      for (int j = 0; j < 4; ++j) sQ[ty*2+i][tx*4+j] = acc[i][j] + bb[j];
  }
  // K = seq @ Wk + bk
  stage_w(sW, Wk, t);
  { float acc[2][4] = {};
    gemm_w2(sA, sW, ty, tx, acc);
    float4 b4 = *(const float4*)&bk[tx*4];
    float bb[4] = {b4.x, b4.y, b4.z, b4.w};
#pragma unroll
    for (int i = 0; i < 2; ++i)
#pragma unroll
      for (int j = 0; j < 4; ++j) sK[ty*2+i][tx*4+j] = acc[i][j] + bb[j];
  }
  // V = seq @ Wv + bv
  stage_w(sW, Wv, t);
  { float acc[2][4] = {};
    gemm_w2(sA, sW, ty, tx, acc);
    float4 b4 = *(const float4*)&bv[tx*4];
    float bb[4] = {b4.x, b4.y, b4.z, b4.w};
#pragma unroll
    for (int i = 0; i < 2; ++i)
#pragma unroll
      for (int j = 0; j < 4; ++j) sV[ty*2+i][tx*4+j] = acc[i][j] + bb[j];
  }
  __syncthreads();

  // scores = Q @ K^T
  { float acc[2][4] = {};
    gemm_bt2(sQ, sK, ty, tx, acc);
#pragma unroll
    for (int i = 0; i < 2; ++i)
#pragma unroll
      for (int j = 0; j < 4; ++j) sP[ty*2+i][tx*4+j] = acc[i][j];
  }
  __syncthreads();

  // masked softmax per row + query mask
  for (int r = wid; r < 64; r += 8){
    float raw = sP[r][lane];
    bool valid = (lane <= r) && (s_msk[lane] != 0.f);
    float sc = valid ? raw * 0.125f : NEGV;
    float m = wmax(sc);
    float e = __expf(sc - m);
    float ssumv = wsum(e);
    sP[r][lane] = (e / ssumv) * s_msk[r];
  }
  __syncthreads();

  // x = attn @ V + q   -> sQ
  { float acc[2][4] = {};
    gemm_wp2(sP, sV, ty, tx, acc);
#pragma unroll
    for (int i = 0; i < 2; ++i)
#pragma unroll
      for (int j = 0; j < 4; ++j){
        int r = ty*2+i, c = tx*4+j;
        sQ[r][c] = acc[i][j] + sq[r][c];
      }
  }
  __syncthreads();

  // LN2: sQ -> sA
  for (int r = wid; r < 64; r += 8){
    float x = sQ[r][lane];
    float mu = wsum(x) * (1.f / 64.f);
    float dv = x - mu;
    float var = wsum(dv * dv) * (1.f / 64.f);
    sA[r][lane] = dv * (1.f / sqrtf(var + EPSV)) * ln2g[lane] + ln2b[lane];
  }
  // h = relu(x2 @ W1 + b1) -> sP  (stage_w's leading sync covers sA writes)
  stage_w(sW, W1, t);
  { float acc[2][4] = {};
    gemm_w2(sA, sW, ty, tx, acc);
    float4 b4 = *(const float4*)&b1[tx*4];
    float bb[4] = {b4.x, b4.y, b4.z, b4.w};
#pragma unroll
    for (int i = 0; i < 2; ++i)
#pragma unroll
      for (int j = 0; j < 4; ++j)
        sP[ty*2+i][tx*4+j] = fmaxf(acc[i][j] + bb[j], 0.f);
  }
  // out = (h @ W2 + b2 + x2) * mask -> global seq
  stage_w(sW, W2, t);
  { float acc[2][4] = {};
    gemm_w2(sP, sW, ty, tx, acc);
    float4 b4 = *(const float4*)&b2[tx*4];
    float bb[4] = {b4.x, b4.y, b4.z, b4.w};
#pragma unroll
    for (int i = 0; i < 2; ++i){
      int r = ty*2+i;
      float m = s_msk[r];
      float4 o;
      o.x = (acc[i][0] + bb[0] + sA[r][tx*4+0]) * m;
      o.y = (acc[i][1] + bb[1] + sA[r][tx*4+1]) * m;
      o.z = (acc[i][2] + bb[2] + sA[r][tx*4+2]) * m;
      o.w = (acc[i][3] + bb[3] + sA[r][tx*4+3]) * m;
      *(float4*)&seq_b[r*64 + tx*4] = o;
    }
  }
}

// ------------------------------------------------------------- final LN ----
__global__ __launch_bounds__(64) void k_lnf(const float* __restrict__ seq,
    const float* __restrict__ g, const float* __restrict__ be,
    float* __restrict__ semb){
  int b = blockIdx.x, lane = threadIdx.x;
  float x = seq[(size_t)b * Ssz * Dsz + 63 * 64 + lane];
  float mu = wsum(x) * (1.f / 64.f);
  float dv = x - mu;
  float var = wsum(dv * dv) * (1.f / 64.f);
  semb[b * 64 + lane] = dv * (1.f / sqrtf(var + EPSV)) * g[lane] + be[lane];
}

// --------------------------------------------------------------- scoring ---
// out[b][i] = sum_d E[b][d]*T[i][d] via bf16 MFMA with hi/lo split:
// out = Eh.Th + Eh.Tl + El.Th  (fp32 accum; dropped El.Tl ~ 2^-18 rel).
// Tile: 64 b-rows x 128 items per WG, 4 waves each own 16 b-rows.
__global__ __launch_bounds__(256) void k_score(const float* __restrict__ E,
    const float* __restrict__ T, float* __restrict__ out){
  __shared__ unsigned short Th[128][72], Tl[128][72];   // pad 72: 8 lanes/bank-grp
  __shared__ unsigned short Eh[64][72],  El[64][72];
  const int t = threadIdx.x;
  const int i0 = blockIdx.x * 128, b0 = blockIdx.y * 64;

  // stage T tile (2048 float4), convert to bf16 hi/lo
#pragma unroll
  for (int it = 0; it < 8; ++it){
    int f4 = t + 256 * it;
    int r = f4 >> 4, c4 = f4 & 15;
    int gi = i0 + r;
    float4 v = make_float4(0.f, 0.f, 0.f, 0.f);
    if (gi < NITEMS) v = ((const float4*)(T + (size_t)gi * 64))[c4];
    float f[4] = {v.x, v.y, v.z, v.w};
#pragma unroll
    for (int j = 0; j < 4; ++j){
      unsigned short h = f2b(f[j]);
      Th[r][c4*4 + j] = h;
      Tl[r][c4*4 + j] = f2b(f[j] - b2f(h));
    }
  }
  // stage E slice (1024 float4)
#pragma unroll
  for (int it = 0; it < 4; ++it){
    int f4 = t + 256 * it;
    int r = f4 >> 4, c4 = f4 & 15;
    float4 v = ((const float4*)(E + (size_t)(b0 + r) * 64))[c4];
    float f[4] = {v.x, v.y, v.z, v.w};
#pragma unroll
    for (int j = 0; j < 4; ++j){
      unsigned short h = f2b(f[j]);
      Eh[r][c4*4 + j] = h;
      El[r][c4*4 + j] = f2b(f[j] - b2f(h));
    }
  }
  __syncthreads();

  const int lane = t & 63, w = t >> 6;     // 4 waves
  const int li = lane & 15, g = lane >> 4; // frag row/col + k-group

  // A frags: rows w*16+li, k = kc*32 + g*8 .. +7
  short8 Ah[2], Al[2];
#pragma unroll
  for (int kc = 0; kc < 2; ++kc){
    Ah[kc] = *(const short8*)&Eh[w*16 + li][kc*32 + g*8];
    Al[kc] = *(const short8*)&El[w*16 + li][kc*32 + g*8];
  }

  f32x4 acc[8];
#pragma unroll
  for (int nt = 0; nt < 8; ++nt) acc[nt] = (f32x4)(0.f);

#pragma unroll
  for (int nt = 0; nt < 8; ++nt){
#pragma unroll
    for (int kc = 0; kc < 2; ++kc){
      short8 bh = *(const short8*)&Th[nt*16 + li][kc*32 + g*8];
      short8 bl = *(const short8*)&Tl[nt*16 + li][kc*32 + g*8];
      acc[nt] = __builtin_amdgcn_mfma_f32_16x16x32_bf16(Ah[kc], bh, acc[nt], 0, 0, 0);
      acc[nt] = __builtin_amdgcn_mfma_f32_16x16x32_bf16(Ah[kc], bl, acc[nt], 0, 0, 0);
      acc[nt] = __builtin_amdgcn_mfma_f32_16x16x32_bf16(Al[kc], bh, acc[nt], 0, 0, 0);
    }
  }

  // C/D: row = b0 + w*16 + g*4 + reg, col = i0 + nt*16 + li  (m89 mapping)
#pragma unroll
  for (int nt = 0; nt < 8; ++nt){
    int col = i0 + nt*16 + li;
    if (col < NITEMS){
      size_t base = (size_t)(b0 + w*16 + g*4) * NITEMS + col;
#pragma unroll
      for (int r = 0; r < 4; ++r)
        out[base + (size_t)r * NITEMS] = acc[nt][r];
    }
  }
}

// ----------------------------------------------------------------- launch --
extern "C" void kernel_launch(void* const* d_in, const int* in_sizes, int n_in,
                              void* d_out, int out_size, void* d_ws, size_t ws_size,
                              hipStream_t stream){
  const int*   ids      = (const int*)  d_in[0];
  const float* item_emb = (const float*)d_in[1];
  const float* pos_emb  = (const float*)d_in[2];
  const float* ln1g     = (const float*)d_in[3];
  const float* ln1b     = (const float*)d_in[4];
  const float* Wq       = (const float*)d_in[5];
  const float* bq       = (const float*)d_in[6];
  const float* Wk       = (const float*)d_in[7];
  const float* bk       = (const float*)d_in[8];
  const float* Wv       = (const float*)d_in[9];
  const float* bv       = (const float*)d_in[10];
  const float* ln2g     = (const float*)d_in[11];
  const float* ln2b     = (const float*)d_in[12];
  const float* W1       = (const float*)d_in[13];
  const float* b1       = (const float*)d_in[14];
  const float* W2       = (const float*)d_in[15];
  const float* b2       = (const float*)d_in[16];
  const float* lnfg     = (const float*)d_in[17];
  const float* lnfb     = (const float*)d_in[18];
  const float* items    = (const float*)d_in[19];
  float* out  = (float*)d_out;
  float* seq  = (float*)d_ws;                       // 512*64*64 f32 = 8 MB
  float* semb = seq + (size_t)Bsz * Ssz * Dsz;      // 512*64 f32

  k_embed<<<2048, 256, 0, stream>>>(ids, item_emb, pos_emb, seq);
  for (int l = 0; l < 2; ++l)
    k_layer<<<Bsz, 512, 0, stream>>>(seq, ids,
        ln1g + l*64, ln1b + l*64,
        Wq + l*4096, bq + l*64, Wk + l*4096, bk + l*64, Wv + l*4096, bv + l*64,
        ln2g + l*64, ln2b + l*64,
        W1 + l*4096, b1 + l*64, W2 + l*4096, b2 + l*64);
  k_lnf<<<Bsz, 64, 0, stream>>>(seq, lnfg, lnfb, semb);
  k_score<<<dim3(1563, 8), 256, 0, stream>>>(semb, items, out);
}

// Round 4
// 251.124 us; speedup vs baseline: 1.5680x; 1.1751x over previous
//
#include <hip/hip_runtime.h>
#include <cstddef>

// SASRec inference. Round 4: k_layer fully on bf16 hi/lo MFMA (all eight
// 64x64 GEMMs), k_score LDS-free with register-resident item fragments.

#define NITEMS 200000
#define Bsz 512
#define Ssz 64
#define Dsz 64
#define EPSV 1e-3f
#define NEGV (-4294967295.0f)   // -2^32 + 1

typedef __attribute__((ext_vector_type(8))) short short8;   // 8 bf16
typedef __attribute__((ext_vector_type(4))) float f32x4;

static __device__ __forceinline__ float wsum(float v){
#pragma unroll
  for (int o = 32; o > 0; o >>= 1) v += __shfl_xor(v, o, 64);
  return v;
}
static __device__ __forceinline__ float wmax(float v){
#pragma unroll
  for (int o = 32; o > 0; o >>= 1) v = fmaxf(v, __shfl_xor(v, o, 64));
  return v;
}

// bf16 round-to-nearest-even (finite inputs only)
static __device__ __forceinline__ unsigned short f2b(float f){
  unsigned u = __float_as_uint(f);
  unsigned r = u + 0x7fffu + ((u >> 16) & 1u);
  return (unsigned short)(r >> 16);
}
static __device__ __forceinline__ float b2f(unsigned short h){
  return __uint_as_float(((unsigned)h) << 16);
}

// ---------------------------------------------------------------- embed ----
__global__ __launch_bounds__(256) void k_embed(const int* __restrict__ ids,
    const float* __restrict__ item_emb, const float* __restrict__ pos_emb,
    float* __restrict__ seq){
  int e4 = blockIdx.x * 256 + threadIdx.x;      // float4 index over [B*S][16]
  int d4 = e4 & 15, bs = e4 >> 4, s = bs & 63;
  int id = ids[bs];
  float4 r = make_float4(0.f, 0.f, 0.f, 0.f);
  if (id != NITEMS){
    float4 a = ((const float4*)(item_emb + (size_t)id * 64))[d4];
    float4 p = ((const float4*)(pos_emb + s * 64))[d4];
    r = make_float4(a.x + p.x, a.y + p.y, a.z + p.z, a.w + p.w);
  }
  ((float4*)seq)[e4] = r;
}

// ------------------------------------------------------ fused block layer --
// Stage a 64x64 f32 weight from global into LDS as bf16 hi/lo, TRANSPOSED
// (Wt[n][k]) so B-fragments are contiguous ds_read_b128.
static __device__ __forceinline__ void stage_wt(unsigned short WH[64][72],
    unsigned short WL[64][72], const float* __restrict__ Wg, int t){
  __syncthreads();
  int k0 = (t >> 4) * 2, n0 = (t & 15) * 4;
  float4 r0 = *(const float4*)&Wg[k0 * 64 + n0];
  float4 r1 = *(const float4*)&Wg[(k0 + 1) * 64 + n0];
  float f0[4] = {r0.x, r0.y, r0.z, r0.w}, f1[4] = {r1.x, r1.y, r1.z, r1.w};
#pragma unroll
  for (int j = 0; j < 4; ++j){
    unsigned short h0 = f2b(f0[j]), h1 = f2b(f1[j]);
    unsigned short l0 = f2b(f0[j] - b2f(h0)), l1 = f2b(f1[j] - b2f(h1));
    *(unsigned*)&WH[n0 + j][k0] = (unsigned)h0 | ((unsigned)h1 << 16);
    *(unsigned*)&WL[n0 + j][k0] = (unsigned)l0 | ((unsigned)l1 << 16);
  }
  __syncthreads();
}

// 64x64 GEMM: A (row-major [m][k] hi/lo) x B (transposed [n][k] hi/lo).
// Wave (qb,cb) computes rows qb*16..+15, cols cb*32..+31 (2 tiles).
// 3-term hi/lo split, fp32 accumulate.
static __device__ __forceinline__ void mm64(
    const unsigned short (*__restrict__ Ah)[72], const unsigned short (*__restrict__ Al)[72],
    const unsigned short (*__restrict__ Bh)[72], const unsigned short (*__restrict__ Bl)[72],
    int qb, int cb, int li, int g, f32x4 acc[2]){
  short8 ah[2], al[2];
#pragma unroll
  for (int kc = 0; kc < 2; ++kc){
    ah[kc] = *(const short8*)&Ah[qb*16 + li][kc*32 + g*8];
    al[kc] = *(const short8*)&Al[qb*16 + li][kc*32 + g*8];
  }
#pragma unroll
  for (int nt = 0; nt < 2; ++nt){
    acc[nt] = (f32x4)(0.f);
#pragma unroll
    for (int kc = 0; kc < 2; ++kc){
      short8 bh = *(const short8*)&Bh[cb*32 + nt*16 + li][kc*32 + g*8];
      short8 bl = *(const short8*)&Bl[cb*32 + nt*16 + li][kc*32 + g*8];
      acc[nt] = __builtin_amdgcn_mfma_f32_16x16x32_bf16(ah[kc], bh, acc[nt], 0, 0, 0);
      acc[nt] = __builtin_amdgcn_mfma_f32_16x16x32_bf16(ah[kc], bl, acc[nt], 0, 0, 0);
      acc[nt] = __builtin_amdgcn_mfma_f32_16x16x32_bf16(al[kc], bh, acc[nt], 0, 0, 0);
    }
  }
}

__global__ __launch_bounds__(512) void k_layer(float* __restrict__ seq_g,
    const int* __restrict__ ids,
    const float* __restrict__ ln1g, const float* __restrict__ ln1b,
    const float* __restrict__ Wq, const float* __restrict__ bq,
    const float* __restrict__ Wk, const float* __restrict__ bk,
    const float* __restrict__ Wv, const float* __restrict__ bv,
    const float* __restrict__ ln2g, const float* __restrict__ ln2b,
    const float* __restrict__ W1, const float* __restrict__ b1,
    const float* __restrict__ W2, const float* __restrict__ b2){
  // f32 buffers (pad 68 floats: rows 16B-aligned for float4 stores)
  __shared__ float F0[64][68];   // seq -> scores -> x (attn out)
  __shared__ float F1[64][68];   // xq (LN1 out) -> x2 (LN2 out)
  // bf16 hi/lo buffers, rows padded to 72 shorts (144B, 16B-aligned)
  // U0: seq -> P ; U1: LN1 out -> LN2 out ; U2: Q -> FFN hidden ; U3: K ; U4: V^T
  __shared__ unsigned short UH[5][64][72], UL[5][64][72];
  __shared__ unsigned short WH[64][72], WL[64][72];
  __shared__ float s_msk[64];

  const int t = threadIdx.x;
  const int lane = t & 63, wid = t >> 6;        // 8 waves
  const int li = lane & 15, g = lane >> 4;
  const int qb = wid & 3, cb = wid >> 2;        // wave tile: rows qb*16, cols cb*32
  const int b = blockIdx.x;
  float* seq_b = seq_g + (size_t)b * Ssz * Dsz;

  // ---- phase 0: load seq -> F0 (f32) + U0 (bf16 h/l) ----
#pragma unroll
  for (int it = 0; it < 2; ++it){
    int e4 = t + 512 * it;
    int r = e4 >> 4, c = (e4 & 15) * 4;
    float4 v = ((const float4*)seq_b)[e4];
    *(float4*)&F0[r][c] = v;
    float f[4] = {v.x, v.y, v.z, v.w};
#pragma unroll
    for (int j = 0; j < 4; ++j){
      unsigned short h = f2b(f[j]);
      UH[0][r][c + j] = h;
      UL[0][r][c + j] = f2b(f[j] - b2f(h));
    }
  }
  if (t < 64) s_msk[t] = (ids[b * Ssz + t] != NITEMS) ? 1.f : 0.f;
  __syncthreads();

  // ---- LN1: F0 -> F1 (f32) + U1 (bf16 h/l) ----
  for (int r = wid; r < 64; r += 8){
    float x = F0[r][lane];
    float mu = wsum(x) * (1.f / 64.f);
    float dv = x - mu;
    float var = wsum(dv * dv) * (1.f / 64.f);
    float o = dv * (1.f / sqrtf(var + EPSV)) * ln1g[lane] + ln1b[lane];
    F1[r][lane] = o;
    unsigned short h = f2b(o);
    UH[1][r][lane] = h;
    UL[1][r][lane] = f2b(o - b2f(h));
  }
  // (stage_wt's leading barrier fences LN1 writes)

  // ---- Q = LN1 @ Wq + bq -> U2 (row-major) ----
  stage_wt(WH, WL, Wq, t);
  { f32x4 acc[2]; mm64(UH[1], UL[1], WH, WL, qb, cb, li, g, acc);
#pragma unroll
    for (int nt = 0; nt < 2; ++nt){
      int col = cb*32 + nt*16 + li;
      float bb = bq[col];
#pragma unroll
      for (int r4 = 0; r4 < 4; ++r4){
        int row = qb*16 + g*4 + r4;
        float qv = acc[nt][r4] + bb;
        unsigned short h = f2b(qv);
        UH[2][row][col] = h; UL[2][row][col] = f2b(qv - b2f(h));
      }
    }
  }
  // ---- K = seq @ Wk + bk -> U3 (row-major [pos][dh] == B-layout for QK^T) ----
  stage_wt(WH, WL, Wk, t);
  { f32x4 acc[2]; mm64(UH[0], UL[0], WH, WL, qb, cb, li, g, acc);
#pragma unroll
    for (int nt = 0; nt < 2; ++nt){
      int col = cb*32 + nt*16 + li;
      float bb = bk[col];
#pragma unroll
      for (int r4 = 0; r4 < 4; ++r4){
        int row = qb*16 + g*4 + r4;
        float kv = acc[nt][r4] + bb;
        unsigned short h = f2b(kv);
        UH[3][row][col] = h; UL[3][row][col] = f2b(kv - b2f(h));
      }
    }
  }
  // ---- V = seq @ Wv + bv -> U4 TRANSPOSED (Vt[dh][pos] == B-layout for PV) ----
  stage_wt(WH, WL, Wv, t);
  { f32x4 acc[2]; mm64(UH[0], UL[0], WH, WL, qb, cb, li, g, acc);
#pragma unroll
    for (int nt = 0; nt < 2; ++nt){
      int col = cb*32 + nt*16 + li;
      float bb = bv[col];
#pragma unroll
      for (int r4 = 0; r4 < 4; ++r4){
        int row = qb*16 + g*4 + r4;
        float vv = acc[nt][r4] + bb;
        unsigned short h = f2b(vv);
        UH[4][col][row] = h; UL[4][col][row] = f2b(vv - b2f(h));
      }
    }
  }
  __syncthreads();

  // ---- scores = Q @ K^T -> F0 (f32) ----
  { f32x4 acc[2]; mm64(UH[2], UL[2], UH[3], UL[3], qb, cb, li, g, acc);
#pragma unroll
    for (int nt = 0; nt < 2; ++nt){
      int col = cb*32 + nt*16 + li;
#pragma unroll
      for (int r4 = 0; r4 < 4; ++r4)
        F0[qb*16 + g*4 + r4][col] = acc[nt][r4];
    }
  }
  __syncthreads();

  // ---- masked softmax: F0 -> U0 (P, bf16 h/l) ----
  for (int r = wid; r < 64; r += 8){
    float raw = F0[r][lane];
    bool valid = (lane <= r) && (s_msk[lane] != 0.f);
    float sc = valid ? raw * 0.125f : NEGV;
    float m = wmax(sc);
    float e = __expf(sc - m);
    float ssumv = wsum(e);
    float p = (e / ssumv) * s_msk[r];
    unsigned short h = f2b(p);
    UH[0][r][lane] = h;
    UL[0][r][lane] = f2b(p - b2f(h));
  }
  __syncthreads();

  // ---- x = P @ V + xq -> F0 (f32) ----
  { f32x4 acc[2]; mm64(UH[0], UL[0], UH[4], UL[4], qb, cb, li, g, acc);
#pragma unroll
    for (int nt = 0; nt < 2; ++nt){
      int col = cb*32 + nt*16 + li;
#pragma unroll
      for (int r4 = 0; r4 < 4; ++r4){
        int row = qb*16 + g*4 + r4;
        F0[row][col] = acc[nt][r4] + F1[row][col];
      }
    }
  }
  __syncthreads();

  // ---- LN2: F0 -> F1 (f32 residual) + U1 (bf16 h/l) ----
  for (int r = wid; r < 64; r += 8){
    float x = F0[r][lane];
    float mu = wsum(x) * (1.f / 64.f);
    float dv = x - mu;
    float var = wsum(dv * dv) * (1.f / 64.f);
    float o = dv * (1.f / sqrtf(var + EPSV)) * ln2g[lane] + ln2b[lane];
    F1[r][lane] = o;
    unsigned short h = f2b(o);
    UH[1][r][lane] = h;
    UL[1][r][lane] = f2b(o - b2f(h));
  }
  // ---- h = relu(x2 @ W1 + b1) -> U2 ----
  stage_wt(WH, WL, W1, t);
  { f32x4 acc[2]; mm64(UH[1], UL[1], WH, WL, qb, cb, li, g, acc);
#pragma unroll
    for (int nt = 0; nt < 2; ++nt){
      int col = cb*32 + nt*16 + li;
      float bb = b1[col];
#pragma unroll
      for (int r4 = 0; r4 < 4; ++r4){
        int row = qb*16 + g*4 + r4;
        float hv = fmaxf(acc[nt][r4] + bb, 0.f);
        unsigned short h = f2b(hv);
        UH[2][row][col] = h; UL[2][row][col] = f2b(hv - b2f(h));
      }
    }
  }
  // ---- out = (h @ W2 + b2 + x2) * mask -> global ----
  stage_wt(WH, WL, W2, t);
  { f32x4 acc[2]; mm64(UH[2], UL[2], WH, WL, qb, cb, li, g, acc);
#pragma unroll
    for (int nt = 0; nt < 2; ++nt){
      int col = cb*32 + nt*16 + li;
      float bb = b2[col];
#pragma unroll
      for (int r4 = 0; r4 < 4; ++r4){
        int row = qb*16 + g*4 + r4;
        seq_b[row*64 + col] = (acc[nt][r4] + bb + F1[row][col]) * s_msk[row];
      }
    }
  }
}

// ------------------------------------------------------------- final LN ----
__global__ __launch_bounds__(64) void k_lnf(const float* __restrict__ seq,
    const float* __restrict__ g, const float* __restrict__ be,
    float* __restrict__ semb){
  int b = blockIdx.x, lane = threadIdx.x;
  float x = seq[(size_t)b * Ssz * Dsz + 63 * 64 + lane];
  float mu = wsum(x) * (1.f / 64.f);
  float dv = x - mu;
  float var = wsum(dv * dv) * (1.f / 64.f);
  semb[b * 64 + lane] = dv * (1.f / sqrtf(var + EPSV)) * g[lane] + be[lane];
}

// --------------------------------------------------------------- scoring ---
// out[b][i] = sum_d E[b][d]*T[i][d], bf16 MFMA hi/lo 3-term split.
// LDS-free: each block keeps its 128-item B-fragments in registers and
// loops over 8 batch chunks of 64 rows; E (128 KB) stays L2-resident.
__global__ __launch_bounds__(256) void k_score(const float* __restrict__ E,
    const float* __restrict__ T, float* __restrict__ out){
  const int t = threadIdx.x, lane = t & 63, w = t >> 6;  // 4 waves
  const int li = lane & 15, g = lane >> 4;
  const int i0 = blockIdx.x * 128;

  // B-fragments: T rows i0+nt*16+li, k = kc*32+g*8..+7
  short8 Bh[16], Bl[16];
#pragma unroll
  for (int nt = 0; nt < 8; ++nt){
    int gi = i0 + nt*16 + li;
    bool ok = gi < NITEMS;
    const float4* tp = (const float4*)(T + (size_t)(ok ? gi : 0) * 64);
#pragma unroll
    for (int kc = 0; kc < 2; ++kc){
      float4 v0 = tp[kc*8 + g*2];
      float4 v1 = tp[kc*8 + g*2 + 1];
      float f[8] = {v0.x,v0.y,v0.z,v0.w,v1.x,v1.y,v1.z,v1.w};
      short8 h, l;
#pragma unroll
      for (int j = 0; j < 8; ++j){
        float fv = ok ? f[j] : 0.f;
        unsigned short hh = f2b(fv);
        h[j] = (short)hh;
        l[j] = (short)f2b(fv - b2f(hh));
      }
      Bh[nt*2 + kc] = h; Bl[nt*2 + kc] = l;
    }
  }

  for (int c = 0; c < 8; ++c){
    int row = c*64 + w*16 + li;
    const float4* ep = (const float4*)(E + (size_t)row * 64);
    short8 Ah[2], Al[2];
#pragma unroll
    for (int kc = 0; kc < 2; ++kc){
      float4 v0 = ep[kc*8 + g*2];
      float4 v1 = ep[kc*8 + g*2 + 1];
      float f[8] = {v0.x,v0.y,v0.z,v0.w,v1.x,v1.y,v1.z,v1.w};
      short8 h, l;
#pragma unroll
      for (int j = 0; j < 8; ++j){
        unsigned short hh = f2b(f[j]);
        h[j] = (short)hh;
        l[j] = (short)f2b(f[j] - b2f(hh));
      }
      Ah[kc] = h; Al[kc] = l;
    }

    f32x4 acc[8];
#pragma unroll
    for (int nt = 0; nt < 8; ++nt) acc[nt] = (f32x4)(0.f);
#pragma unroll
    for (int kc = 0; kc < 2; ++kc){
#pragma unroll
      for (int nt = 0; nt < 8; ++nt)
        acc[nt] = __builtin_amdgcn_mfma_f32_16x16x32_bf16(Ah[kc], Bh[nt*2+kc], acc[nt], 0, 0, 0);
#pragma unroll
      for (int nt = 0; nt < 8; ++nt)
        acc[nt] = __builtin_amdgcn_mfma_f32_16x16x32_bf16(Ah[kc], Bl[nt*2+kc], acc[nt], 0, 0, 0);
#pragma unroll
      for (int nt = 0; nt < 8; ++nt)
        acc[nt] = __builtin_amdgcn_mfma_f32_16x16x32_bf16(Al[kc], Bh[nt*2+kc], acc[nt], 0, 0, 0);
    }

#pragma unroll
    for (int nt = 0; nt < 8; ++nt){
      int col = i0 + nt*16 + li;
      if (col < NITEMS){
        size_t base = (size_t)(c*64 + w*16 + g*4) * NITEMS + col;
#pragma unroll
        for (int r = 0; r < 4; ++r)
          out[base + (size_t)r * NITEMS] = acc[nt][r];
      }
    }
  }
}

// ----------------------------------------------------------------- launch --
extern "C" void kernel_launch(void* const* d_in, const int* in_sizes, int n_in,
                              void* d_out, int out_size, void* d_ws, size_t ws_size,
                              hipStream_t stream){
  const int*   ids      = (const int*)  d_in[0];
  const float* item_emb = (const float*)d_in[1];
  const float* pos_emb  = (const float*)d_in[2];
  const float* ln1g     = (const float*)d_in[3];
  const float* ln1b     = (const float*)d_in[4];
  const float* Wq       = (const float*)d_in[5];
  const float* bq       = (const float*)d_in[6];
  const float* Wk       = (const float*)d_in[7];
  const float* bk       = (const float*)d_in[8];
  const float* Wv       = (const float*)d_in[9];
  const float* bv       = (const float*)d_in[10];
  const float* ln2g     = (const float*)d_in[11];
  const float* ln2b     = (const float*)d_in[12];
  const float* W1       = (const float*)d_in[13];
  const float* b1       = (const float*)d_in[14];
  const float* W2       = (const float*)d_in[15];
  const float* b2       = (const float*)d_in[16];
  const float* lnfg     = (const float*)d_in[17];
  const float* lnfb     = (const float*)d_in[18];
  const float* items    = (const float*)d_in[19];
  float* out  = (float*)d_out;
  float* seq  = (float*)d_ws;                       // 512*64*64 f32 = 8 MB
  float* semb = seq + (size_t)Bsz * Ssz * Dsz;      // 512*64 f32

  k_embed<<<2048, 256, 0, stream>>>(ids, item_emb, pos_emb, seq);
  for (int l = 0; l < 2; ++l)
    k_layer<<<Bsz, 512, 0, stream>>>(seq, ids,
        ln1g + l*64, ln1b + l*64,
        Wq + l*4096, bq + l*64, Wk + l*4096, bk + l*64, Wv + l*4096, bv + l*64,
        ln2g + l*64, ln2b + l*64,
        W1 + l*4096, b1 + l*64, W2 + l*4096, b2 + l*64);
  k_lnf<<<Bsz, 64, 0, stream>>>(seq, lnfg, lnfb, semb);
  k_score<<<1563, 256, 0, stream>>>(semb, items, out);
}

// Round 5
// 236.304 us; speedup vs baseline: 1.6663x; 1.0627x over previous
//
#include <hip/hip_runtime.h>
#include <cstddef>

// SASRec inference. Round 5: k_score VGPR-pressure fix (64-item tiles,
// 4 waves/SIMD, NT stores); k_layer weight preload into registers.

#define NITEMS 200000
#define Bsz 512
#define Ssz 64
#define Dsz 64
#define EPSV 1e-3f
#define NEGV (-4294967295.0f)   // -2^32 + 1

typedef __attribute__((ext_vector_type(8))) short short8;   // 8 bf16
typedef __attribute__((ext_vector_type(4))) float f32x4;

static __device__ __forceinline__ float wsum(float v){
#pragma unroll
  for (int o = 32; o > 0; o >>= 1) v += __shfl_xor(v, o, 64);
  return v;
}
static __device__ __forceinline__ float wmax(float v){
#pragma unroll
  for (int o = 32; o > 0; o >>= 1) v = fmaxf(v, __shfl_xor(v, o, 64));
  return v;
}

// bf16 round-to-nearest-even (finite inputs only)
static __device__ __forceinline__ unsigned short f2b(float f){
  unsigned u = __float_as_uint(f);
  unsigned r = u + 0x7fffu + ((u >> 16) & 1u);
  return (unsigned short)(r >> 16);
}
static __device__ __forceinline__ float b2f(unsigned short h){
  return __uint_as_float(((unsigned)h) << 16);
}

// ---------------------------------------------------------------- embed ----
__global__ __launch_bounds__(256) void k_embed(const int* __restrict__ ids,
    const float* __restrict__ item_emb, const float* __restrict__ pos_emb,
    float* __restrict__ seq){
  int e4 = blockIdx.x * 256 + threadIdx.x;      // float4 index over [B*S][16]
  int d4 = e4 & 15, bs = e4 >> 4, s = bs & 63;
  int id = ids[bs];
  float4 r = make_float4(0.f, 0.f, 0.f, 0.f);
  if (id != NITEMS){
    float4 a = ((const float4*)(item_emb + (size_t)id * 64))[d4];
    float4 p = ((const float4*)(pos_emb + s * 64))[d4];
    r = make_float4(a.x + p.x, a.y + p.y, a.z + p.z, a.w + p.w);
  }
  ((float4*)seq)[e4] = r;
}

// ------------------------------------------------------ fused block layer --
// Write a preloaded 64x64 weight (2 rows k0,k0+1 x 4 cols per thread) into
// LDS as bf16 hi/lo TRANSPOSED (Wt[n][k]) for contiguous B-frag ds_read_b128.
static __device__ __forceinline__ void stage_wr(unsigned short WH[64][72],
    unsigned short WL[64][72], float4 r0, float4 r1, int t){
  __syncthreads();                 // fence previous consumers of WH/WL
  int k0 = (t >> 4) * 2, n0 = (t & 15) * 4;
  float f0[4] = {r0.x, r0.y, r0.z, r0.w}, f1[4] = {r1.x, r1.y, r1.z, r1.w};
#pragma unroll
  for (int j = 0; j < 4; ++j){
    unsigned short h0 = f2b(f0[j]), h1 = f2b(f1[j]);
    unsigned short l0 = f2b(f0[j] - b2f(h0)), l1 = f2b(f1[j] - b2f(h1));
    *(unsigned*)&WH[n0 + j][k0] = (unsigned)h0 | ((unsigned)h1 << 16);
    *(unsigned*)&WL[n0 + j][k0] = (unsigned)l0 | ((unsigned)l1 << 16);
  }
  __syncthreads();
}

// 64x64 GEMM: A (row-major [m][k] hi/lo) x B (transposed [n][k] hi/lo).
// Wave (qb,cb) computes rows qb*16..+15, cols cb*32..+31 (2 tiles).
// 3-term hi/lo split, fp32 accumulate.
static __device__ __forceinline__ void mm64(
    const unsigned short (*__restrict__ Ah)[72], const unsigned short (*__restrict__ Al)[72],
    const unsigned short (*__restrict__ Bh)[72], const unsigned short (*__restrict__ Bl)[72],
    int qb, int cb, int li, int g, f32x4 acc[2]){
  short8 ah[2], al[2];
#pragma unroll
  for (int kc = 0; kc < 2; ++kc){
    ah[kc] = *(const short8*)&Ah[qb*16 + li][kc*32 + g*8];
    al[kc] = *(const short8*)&Al[qb*16 + li][kc*32 + g*8];
  }
#pragma unroll
  for (int nt = 0; nt < 2; ++nt){
    acc[nt] = (f32x4)(0.f);
#pragma unroll
    for (int kc = 0; kc < 2; ++kc){
      short8 bh = *(const short8*)&Bh[cb*32 + nt*16 + li][kc*32 + g*8];
      short8 bl = *(const short8*)&Bl[cb*32 + nt*16 + li][kc*32 + g*8];
      acc[nt] = __builtin_amdgcn_mfma_f32_16x16x32_bf16(ah[kc], bh, acc[nt], 0, 0, 0);
      acc[nt] = __builtin_amdgcn_mfma_f32_16x16x32_bf16(ah[kc], bl, acc[nt], 0, 0, 0);
      acc[nt] = __builtin_amdgcn_mfma_f32_16x16x32_bf16(al[kc], bh, acc[nt], 0, 0, 0);
    }
  }
}

__global__ __launch_bounds__(512) void k_layer(float* __restrict__ seq_g,
    const int* __restrict__ ids,
    const float* __restrict__ ln1g, const float* __restrict__ ln1b,
    const float* __restrict__ Wq, const float* __restrict__ bq,
    const float* __restrict__ Wk, const float* __restrict__ bk,
    const float* __restrict__ Wv, const float* __restrict__ bv,
    const float* __restrict__ ln2g, const float* __restrict__ ln2b,
    const float* __restrict__ W1, const float* __restrict__ b1,
    const float* __restrict__ W2, const float* __restrict__ b2){
  // f32 buffers (pad 68 floats: rows 16B-aligned for float4 stores)
  __shared__ float F0[64][68];   // seq -> scores -> x (attn out)
  __shared__ float F1[64][68];   // xq (LN1 out) -> x2 (LN2 out)
  // bf16 hi/lo buffers, rows padded to 72 shorts (144B, 16B-aligned)
  // U0: seq -> P ; U1: LN1 out -> LN2 out ; U2: Q -> FFN hidden ; U3: K ; U4: V^T
  __shared__ unsigned short UH[5][64][72], UL[5][64][72];
  __shared__ unsigned short WH[64][72], WL[64][72];
  __shared__ float s_msk[64];

  const int t = threadIdx.x;
  const int lane = t & 63, wid = t >> 6;        // 8 waves
  const int li = lane & 15, g = lane >> 4;
  const int qb = wid & 3, cb = wid >> 2;        // wave tile: rows qb*16, cols cb*32
  const int b = blockIdx.x;
  float* seq_b = seq_g + (size_t)b * Ssz * Dsz;

  // ---- preload all 5 weights into VGPRs (latency hidden under phase 0/LN1)
  const float* Ws[5] = {Wq, Wk, Wv, W1, W2};
  const int k0 = (t >> 4) * 2, n0 = (t & 15) * 4;
  float4 wr[10];
#pragma unroll
  for (int m = 0; m < 5; ++m){
    wr[m*2]   = *(const float4*)&Ws[m][k0 * 64 + n0];
    wr[m*2+1] = *(const float4*)&Ws[m][(k0 + 1) * 64 + n0];
  }

  // ---- phase 0: load seq -> F0 (f32) + U0 (bf16 h/l) ----
#pragma unroll
  for (int it = 0; it < 2; ++it){
    int e4 = t + 512 * it;
    int r = e4 >> 4, c = (e4 & 15) * 4;
    float4 v = ((const float4*)seq_b)[e4];
    *(float4*)&F0[r][c] = v;
    float f[4] = {v.x, v.y, v.z, v.w};
#pragma unroll
    for (int j = 0; j < 4; ++j){
      unsigned short h = f2b(f[j]);
      UH[0][r][c + j] = h;
      UL[0][r][c + j] = f2b(f[j] - b2f(h));
    }
  }
  if (t < 64) s_msk[t] = (ids[b * Ssz + t] != NITEMS) ? 1.f : 0.f;
  __syncthreads();

  // ---- LN1: F0 -> F1 (f32) + U1 (bf16 h/l) ----
  for (int r = wid; r < 64; r += 8){
    float x = F0[r][lane];
    float mu = wsum(x) * (1.f / 64.f);
    float dv = x - mu;
    float var = wsum(dv * dv) * (1.f / 64.f);
    float o = dv * (1.f / sqrtf(var + EPSV)) * ln1g[lane] + ln1b[lane];
    F1[r][lane] = o;
    unsigned short h = f2b(o);
    UH[1][r][lane] = h;
    UL[1][r][lane] = f2b(o - b2f(h));
  }
  // (stage_wr's leading barrier fences LN1 writes)

  // ---- Q = LN1 @ Wq + bq -> U2 (row-major) ----
  stage_wr(WH, WL, wr[0], wr[1], t);
  { f32x4 acc[2]; mm64(UH[1], UL[1], WH, WL, qb, cb, li, g, acc);
#pragma unroll
    for (int nt = 0; nt < 2; ++nt){
      int col = cb*32 + nt*16 + li;
      float bb = bq[col];
#pragma unroll
      for (int r4 = 0; r4 < 4; ++r4){
        int row = qb*16 + g*4 + r4;
        float qv = acc[nt][r4] + bb;
        unsigned short h = f2b(qv);
        UH[2][row][col] = h; UL[2][row][col] = f2b(qv - b2f(h));
      }
    }
  }
  // ---- K = seq @ Wk + bk -> U3 (row-major [pos][dh] == B-layout for QK^T) ----
  stage_wr(WH, WL, wr[2], wr[3], t);
  { f32x4 acc[2]; mm64(UH[0], UL[0], WH, WL, qb, cb, li, g, acc);
#pragma unroll
    for (int nt = 0; nt < 2; ++nt){
      int col = cb*32 + nt*16 + li;
      float bb = bk[col];
#pragma unroll
      for (int r4 = 0; r4 < 4; ++r4){
        int row = qb*16 + g*4 + r4;
        float kv = acc[nt][r4] + bb;
        unsigned short h = f2b(kv);
        UH[3][row][col] = h; UL[3][row][col] = f2b(kv - b2f(h));
      }
    }
  }
  // ---- V = seq @ Wv + bv -> U4 TRANSPOSED (Vt[dh][pos] == B-layout for PV) ----
  stage_wr(WH, WL, wr[4], wr[5], t);
  { f32x4 acc[2]; mm64(UH[0], UL[0], WH, WL, qb, cb, li, g, acc);
#pragma unroll
    for (int nt = 0; nt < 2; ++nt){
      int col = cb*32 + nt*16 + li;
      float bb = bv[col];
#pragma unroll
      for (int r4 = 0; r4 < 4; ++r4){
        int row = qb*16 + g*4 + r4;
        float vv = acc[nt][r4] + bb;
        unsigned short h = f2b(vv);
        UH[4][col][row] = h; UL[4][col][row] = f2b(vv - b2f(h));
      }
    }
  }
  __syncthreads();

  // ---- scores = Q @ K^T -> F0 (f32) ----
  { f32x4 acc[2]; mm64(UH[2], UL[2], UH[3], UL[3], qb, cb, li, g, acc);
#pragma unroll
    for (int nt = 0; nt < 2; ++nt){
      int col = cb*32 + nt*16 + li;
#pragma unroll
      for (int r4 = 0; r4 < 4; ++r4)
        F0[qb*16 + g*4 + r4][col] = acc[nt][r4];
    }
  }
  __syncthreads();

  // ---- masked softmax: F0 -> U0 (P, bf16 h/l) ----
  for (int r = wid; r < 64; r += 8){
    float raw = F0[r][lane];
    bool valid = (lane <= r) && (s_msk[lane] != 0.f);
    float sc = valid ? raw * 0.125f : NEGV;
    float m = wmax(sc);
    float e = __expf(sc - m);
    float ssumv = wsum(e);
    float p = (e / ssumv) * s_msk[r];
    unsigned short h = f2b(p);
    UH[0][r][lane] = h;
    UL[0][r][lane] = f2b(p - b2f(h));
  }
  __syncthreads();

  // ---- x = P @ V + xq -> F0 (f32) ----
  { f32x4 acc[2]; mm64(UH[0], UL[0], UH[4], UL[4], qb, cb, li, g, acc);
#pragma unroll
    for (int nt = 0; nt < 2; ++nt){
      int col = cb*32 + nt*16 + li;
#pragma unroll
      for (int r4 = 0; r4 < 4; ++r4){
        int row = qb*16 + g*4 + r4;
        F0[row][col] = acc[nt][r4] + F1[row][col];
      }
    }
  }
  __syncthreads();

  // ---- LN2: F0 -> F1 (f32 residual) + U1 (bf16 h/l) ----
  for (int r = wid; r < 64; r += 8){
    float x = F0[r][lane];
    float mu = wsum(x) * (1.f / 64.f);
    float dv = x - mu;
    float var = wsum(dv * dv) * (1.f / 64.f);
    float o = dv * (1.f / sqrtf(var + EPSV)) * ln2g[lane] + ln2b[lane];
    F1[r][lane] = o;
    unsigned short h = f2b(o);
    UH[1][r][lane] = h;
    UL[1][r][lane] = f2b(o - b2f(h));
  }
  // ---- h = relu(x2 @ W1 + b1) -> U2 ----
  stage_wr(WH, WL, wr[6], wr[7], t);
  { f32x4 acc[2]; mm64(UH[1], UL[1], WH, WL, qb, cb, li, g, acc);
#pragma unroll
    for (int nt = 0; nt < 2; ++nt){
      int col = cb*32 + nt*16 + li;
      float bb = b1[col];
#pragma unroll
      for (int r4 = 0; r4 < 4; ++r4){
        int row = qb*16 + g*4 + r4;
        float hv = fmaxf(acc[nt][r4] + bb, 0.f);
        unsigned short h = f2b(hv);
        UH[2][row][col] = h; UL[2][row][col] = f2b(hv - b2f(h));
      }
    }
  }
  // ---- out = (h @ W2 + b2 + x2) * mask -> global ----
  stage_wr(WH, WL, wr[8], wr[9], t);
  { f32x4 acc[2]; mm64(UH[2], UL[2], WH, WL, qb, cb, li, g, acc);
#pragma unroll
    for (int nt = 0; nt < 2; ++nt){
      int col = cb*32 + nt*16 + li;
      float bb = b2[col];
#pragma unroll
      for (int r4 = 0; r4 < 4; ++r4){
        int row = qb*16 + g*4 + r4;
        seq_b[row*64 + col] = (acc[nt][r4] + bb + F1[row][col]) * s_msk[row];
      }
    }
  }
}

// ------------------------------------------------------------- final LN ----
__global__ __launch_bounds__(64) void k_lnf(const float* __restrict__ seq,
    const float* __restrict__ g, const float* __restrict__ be,
    float* __restrict__ semb){
  int b = blockIdx.x, lane = threadIdx.x;
  float x = seq[(size_t)b * Ssz * Dsz + 63 * 64 + lane];
  float mu = wsum(x) * (1.f / 64.f);
  float dv = x - mu;
  float var = wsum(dv * dv) * (1.f / 64.f);
  semb[b * 64 + lane] = dv * (1.f / sqrtf(var + EPSV)) * g[lane] + be[lane];
}

// --------------------------------------------------------------- scoring ---
// out[b][i] = sum_d E[b][d]*T[i][d], bf16 MFMA hi/lo 3-term split.
// 64-item tile per block (3125 = 200000/64 exactly), B-frags in 64 VGPRs,
// 4 waves/SIMD pinned, NT stores. Loops all 512 batch rows in 8 chunks.
__global__ __launch_bounds__(256, 4) void k_score(const float* __restrict__ E,
    const float* __restrict__ T, float* __restrict__ out){
  const int t = threadIdx.x, lane = t & 63, w = t >> 6;  // 4 waves
  const int li = lane & 15, g = lane >> 4;
  const int i0 = blockIdx.x * 64;

  // B-frags: T rows i0+nt*16+li (always < NITEMS), k = kc*32+g*8..+7
  short8 Bh[8], Bl[8];
#pragma unroll
  for (int nt = 0; nt < 4; ++nt){
    const float4* tp = (const float4*)(T + (size_t)(i0 + nt*16 + li) * 64);
#pragma unroll
    for (int kc = 0; kc < 2; ++kc){
      float4 v0 = tp[kc*8 + g*2];
      float4 v1 = tp[kc*8 + g*2 + 1];
      float f[8] = {v0.x,v0.y,v0.z,v0.w,v1.x,v1.y,v1.z,v1.w};
      short8 h, l;
#pragma unroll
      for (int j = 0; j < 8; ++j){
        unsigned short hh = f2b(f[j]);
        h[j] = (short)hh;
        l[j] = (short)f2b(f[j] - b2f(hh));
      }
      Bh[nt*2 + kc] = h; Bl[nt*2 + kc] = l;
    }
  }

  for (int c = 0; c < 8; ++c){
    int row = c*64 + w*16 + li;
    const float4* ep = (const float4*)(E + (size_t)row * 64);
    short8 Ah[2], Al[2];
#pragma unroll
    for (int kc = 0; kc < 2; ++kc){
      float4 v0 = ep[kc*8 + g*2];
      float4 v1 = ep[kc*8 + g*2 + 1];
      float f[8] = {v0.x,v0.y,v0.z,v0.w,v1.x,v1.y,v1.z,v1.w};
      short8 h, l;
#pragma unroll
      for (int j = 0; j < 8; ++j){
        unsigned short hh = f2b(f[j]);
        h[j] = (short)hh;
        l[j] = (short)f2b(f[j] - b2f(hh));
      }
      Ah[kc] = h; Al[kc] = l;
    }

    f32x4 acc[4];
#pragma unroll
    for (int nt = 0; nt < 4; ++nt) acc[nt] = (f32x4)(0.f);
#pragma unroll
    for (int kc = 0; kc < 2; ++kc){
#pragma unroll
      for (int nt = 0; nt < 4; ++nt)
        acc[nt] = __builtin_amdgcn_mfma_f32_16x16x32_bf16(Ah[kc], Bh[nt*2+kc], acc[nt], 0, 0, 0);
#pragma unroll
      for (int nt = 0; nt < 4; ++nt)
        acc[nt] = __builtin_amdgcn_mfma_f32_16x16x32_bf16(Ah[kc], Bl[nt*2+kc], acc[nt], 0, 0, 0);
#pragma unroll
      for (int nt = 0; nt < 4; ++nt)
        acc[nt] = __builtin_amdgcn_mfma_f32_16x16x32_bf16(Al[kc], Bh[nt*2+kc], acc[nt], 0, 0, 0);
    }

    // C/D: row = c*64 + w*16 + g*4 + r, col = i0 + nt*16 + li
#pragma unroll
    for (int nt = 0; nt < 4; ++nt){
      size_t base = (size_t)(c*64 + w*16 + g*4) * NITEMS + i0 + nt*16 + li;
#pragma unroll
      for (int r = 0; r < 4; ++r)
        __builtin_nontemporal_store(acc[nt][r], &out[base + (size_t)r * NITEMS]);
    }
  }
}

// ----------------------------------------------------------------- launch --
extern "C" void kernel_launch(void* const* d_in, const int* in_sizes, int n_in,
                              void* d_out, int out_size, void* d_ws, size_t ws_size,
                              hipStream_t stream){
  const int*   ids      = (const int*)  d_in[0];
  const float* item_emb = (const float*)d_in[1];
  const float* pos_emb  = (const float*)d_in[2];
  const float* ln1g     = (const float*)d_in[3];
  const float* ln1b     = (const float*)d_in[4];
  const float* Wq       = (const float*)d_in[5];
  const float* bq       = (const float*)d_in[6];
  const float* Wk       = (const float*)d_in[7];
  const float* bk       = (const float*)d_in[8];
  const float* Wv       = (const float*)d_in[9];
  const float* bv       = (const float*)d_in[10];
  const float* ln2g     = (const float*)d_in[11];
  const float* ln2b     = (const float*)d_in[12];
  const float* W1       = (const float*)d_in[13];
  const float* b1       = (const float*)d_in[14];
  const float* W2       = (const float*)d_in[15];
  const float* b2       = (const float*)d_in[16];
  const float* lnfg     = (const float*)d_in[17];
  const float* lnfb     = (const float*)d_in[18];
  const float* items    = (const float*)d_in[19];
  float* out  = (float*)d_out;
  float* seq  = (float*)d_ws;                       // 512*64*64 f32 = 8 MB
  float* semb = seq + (size_t)Bsz * Ssz * Dsz;      // 512*64 f32

  k_embed<<<2048, 256, 0, stream>>>(ids, item_emb, pos_emb, seq);
  for (int l = 0; l < 2; ++l)
    k_layer<<<Bsz, 512, 0, stream>>>(seq, ids,
        ln1g + l*64, ln1b + l*64,
        Wq + l*4096, bq + l*64, Wk + l*4096, bk + l*64, Wv + l*4096, bv + l*64,
        ln2g + l*64, ln2b + l*64,
        W1 + l*4096, b1 + l*64, W2 + l*4096, b2 + l*64);
  k_lnf<<<Bsz, 64, 0, stream>>>(seq, lnfg, lnfb, semb);
  k_score<<<3125, 256, 0, stream>>>(semb, items, out);
}